// Round 4
// baseline (143.287 us; speedup 1.0000x reference)
//
#include <hip/hip_runtime.h>
#include <math.h>

#define ALPHA_C (-0.01f)
#define BLOCKT 320       // 5 waves
#define NWIN 63          // windows resolved per block
#define NB50 320         // 50-blocks per block = 5*(NWIN+1)
#define SPANF 16000      // floats staged = NB50*50 (64 KB)

__global__ __launch_bounds__(BLOCKT)
void softmin_dtw_kernel(const float* __restrict__ x, const float* __restrict__ S,
                        float* __restrict__ out, long long Q, int W,
                        float inv_W) {
  __shared__ __align__(16) float sX[SPANF];  // x stage; aliased for combine bufs
  __shared__ float sYY[5];

  const int tid = threadIdx.x;
  const long long base = 15750LL * blockIdx.x;  // NWIN*250 stride

  // ---- Stage x span (64 KB), coalesced float4 ----
  #pragma unroll
  for (int r = 0; r < 13; ++r) {
    const int idx = r * BLOCKT + tid;
    if (idx < SPANF / 4) {
      const long long gp = base + 4LL * idx;
      float4 v;
      if (gp + 4 <= Q) {
        v = *reinterpret_cast<const float4*>(&x[gp]);
      } else {
        v.x = (gp     < Q) ? x[gp]     : 0.f;
        v.y = (gp + 1 < Q) ? x[gp + 1] : 0.f;
        v.z = (gp + 2 < Q) ? x[gp + 2] : 0.f;
        v.w = (gp + 3 < Q) ? x[gp + 3] : 0.f;
      }
      *reinterpret_cast<float4*>(&sX[4 * idx]) = v;
    }
  }

  // yy[j] once per block (5 threads, global reads, tiny)
  if (tid < 5) {
    float a = 0.f;
    #pragma unroll 10
    for (int s = 0; s < 100; s += 2) {
      const float2 v = *reinterpret_cast<const float2*>(&S[tid * 100 + s]);
      a = fmaf(v.x, v.x, fmaf(v.y, v.y, a));
    }
    sYY[tid] = a;
  }
  __syncthreads();

  // ---- Per-50-block dots: wave-uniform S rows via scalar loads ----
  const int wv = __builtin_amdgcn_readfirstlane(tid >> 6);  // 0..4, SGPR
  const int l = tid & 63;
  const int b = 5 * l + wv;            // this thread's 50-block
  const int i0 = (3 * wv) % 5;         // wave-uniform segment (first-half role)
  const int i1 = (i0 + 2) % 5;         // second-half role
  // Uniform S row pointers -> s_load from scalar cache
  const float* __restrict__ Sa0 = S + (i0 > 0 ? i0 - 1 : 0) * 100;
  const float* __restrict__ Sa1 = S + i0 * 100;
  const float* __restrict__ Sa2 = S + (i0 < 4 ? i0 + 1 : 4) * 100;
  const float* __restrict__ Sb0 = S + (i1 > 0 ? i1 - 1 : 0) * 100 + 50;
  const float* __restrict__ Sb1 = S + i1 * 100 + 50;
  const float* __restrict__ Sb2 = S + (i1 < 4 ? i1 + 1 : 4) * 100 + 50;

  float sq = 0.f, A0 = 0.f, A1 = 0.f, A2 = 0.f, B0 = 0.f, B1 = 0.f, B2 = 0.f;
  const int xb = 50 * b;
  #pragma unroll
  for (int t = 0; t < 50; t += 2) {
    const float2 xv = *reinterpret_cast<const float2*>(&sX[xb + t]);
    float2 y;
    sq = fmaf(xv.x, xv.x, fmaf(xv.y, xv.y, sq));
    y = *reinterpret_cast<const float2*>(&Sa0[t]);
    A0 = fmaf(xv.x, y.x, fmaf(xv.y, y.y, A0));
    y = *reinterpret_cast<const float2*>(&Sa1[t]);
    A1 = fmaf(xv.x, y.x, fmaf(xv.y, y.y, A1));
    y = *reinterpret_cast<const float2*>(&Sa2[t]);
    A2 = fmaf(xv.x, y.x, fmaf(xv.y, y.y, A2));
    y = *reinterpret_cast<const float2*>(&Sb0[t]);
    B0 = fmaf(xv.x, y.x, fmaf(xv.y, y.y, B0));
    y = *reinterpret_cast<const float2*>(&Sb1[t]);
    B1 = fmaf(xv.x, y.x, fmaf(xv.y, y.y, B1));
    y = *reinterpret_cast<const float2*>(&Sb2[t]);
    B2 = fmaf(xv.x, y.x, fmaf(xv.y, y.y, B2));
  }

  // ---- Neighbor combine via LDS (alias sX after all reads done) ----
  __syncthreads();
  float4* exch = reinterpret_cast<float4*>(sX);        // [NB50]
  float4* cw = reinterpret_cast<float4*>(sX) + NB50;   // [NWIN*5]
  {
    float4 ex;
    ex.x = sq; ex.y = B0; ex.z = B1; ex.w = B2;
    exch[b] = ex;
  }
  __syncthreads();
  // First-half window of block b: 5*w0 + 2*i0 = b  ->  w0 = (b - 2*i0)/5
  const int w0 = (b - 2 * i0) / 5;   // exact; = l or l-1 depending on wave
  if (w0 >= 0 && w0 < NWIN) {
    const float4 nx = exch[b + 1];   // partner's {sq, B0, B1, B2}; i1(b+1)==i0(b)... (see proof)
    float4 c;
    c.x = sq + nx.x;                 // xx[i0]
    c.y = A0 + nx.y;                 // xy[i0][i0-1]
    c.z = A1 + nx.z;                 // xy[i0][i0]
    c.w = A2 + nx.w;                 // xy[i0][i0+1]
    cw[w0 * 5 + i0] = c;
  }
  __syncthreads();

  // ---- DTW + exp per window (wave 0, threads 0..NWIN-1) ----
  float xi = 0.f;
  if (tid < NWIN) {
    const long long w = (long long)blockIdx.x * NWIN + tid;
    if (w < W) {
      const float yy0 = sYY[0], yy1 = sYY[1], yy2 = sYY[2], yy3 = sYY[3],
                  yy4 = sYY[4];
      const float4 c0 = cw[tid * 5 + 0];
      const float4 c1 = cw[tid * 5 + 1];
      const float4 c2 = cw[tid * 5 + 2];
      const float4 c3 = cw[tid * 5 + 3];
      const float4 c4 = cw[tid * 5 + 4];

      const float C00 = c0.x + yy0 - 2.f * c0.z;
      const float C01 = c0.x + yy1 - 2.f * c0.w;
      const float C10 = c1.x + yy0 - 2.f * c1.y;
      const float C11 = c1.x + yy1 - 2.f * c1.z;
      const float C12 = c1.x + yy2 - 2.f * c1.w;
      const float C21 = c2.x + yy1 - 2.f * c2.y;
      const float C22 = c2.x + yy2 - 2.f * c2.z;
      const float C23 = c2.x + yy3 - 2.f * c2.w;
      const float C32 = c3.x + yy2 - 2.f * c3.y;
      const float C33 = c3.x + yy3 - 2.f * c3.z;
      const float C34 = c3.x + yy4 - 2.f * c3.w;
      const float C43 = c4.x + yy3 - 2.f * c4.y;
      const float C44 = c4.x + yy4 - 2.f * c4.z;

      const float c11v = C00;
      const float c12v = C01 + c11v;
      const float c21v = C10 + c11v;
      const float c22v = C11 + fminf(fminf(c12v, c21v), c11v);
      const float c23v = C12 + fminf(c22v, c12v);
      const float c32v = C21 + fminf(c22v, c21v);
      const float c33v = C22 + fminf(fminf(c23v, c32v), c22v);
      const float c34v = C23 + fminf(c33v, c23v);
      const float c43v = C32 + fminf(c33v, c32v);
      const float c44v = C33 + fminf(fminf(c34v, c43v), c33v);
      const float c45v = C34 + fminf(c44v, c34v);
      const float c54v = C43 + fminf(c44v, c43v);
      const float c55v = C44 + fminf(fminf(c45v, c54v), c44v);

      xi = expf(ALPHA_C * sqrtf(fmaxf(c55v, 0.f)));
    }
  }

  // Wave 0 reduce + one atomic per block
  if (tid < 64) {
    #pragma unroll
    for (int off = 32; off > 0; off >>= 1) xi += __shfl_down(xi, off);
    if (tid == 0) atomicAdd(out, xi * inv_W);
  }
}

extern "C" void kernel_launch(void* const* d_in, const int* in_sizes, int n_in,
                              void* d_out, int out_size, void* d_ws, size_t ws_size,
                              hipStream_t stream) {
  const float* x = (const float*)d_in[0];
  const float* S = (const float*)d_in[1];
  float* out = (float*)d_out;

  const long long Q = in_sizes[0];
  const int L = in_sizes[1];   // 500
  const int step = L / 2;      // 250
  const long long n = Q - L;
  const int W = (int)((n + step - 1) / step);  // 79998

  hipMemsetAsync(out, 0, sizeof(float), stream);

  const int blocks = (W + NWIN - 1) / NWIN;  // 1270
  softmin_dtw_kernel<<<blocks, BLOCKT, 0, stream>>>(x, S, out, Q, W,
                                                    1.0f / (float)W);
}

// Round 5
// 133.831 us; speedup vs baseline: 1.0707x; 1.0707x over previous
//
#include <hip/hip_runtime.h>
#include <math.h>

#define ALPHA_C (-0.01f)
#define BLOCK 256
#define NWIN 50      // windows per block
#define SROW 52      // padded S half-row stride (52 floats = 208 B = 13*16B)

__global__ __launch_bounds__(BLOCK)
void softmin_dtw_kernel(const float* __restrict__ x, const float* __restrict__ S,
                        float* __restrict__ out, long long Q, int W,
                        float inv_W) {
  __shared__ __align__(16) float sS[10 * SROW];  // rows 0-4: S[j][0:50], 5-9: S[j][50:100]
  __shared__ float sYY[5];
  __shared__ __align__(16) float4 exch[BLOCK];   // {sq, B0, B1, B2}
  __shared__ __align__(16) float4 cw[NWIN * 5];  // {xx, xy[i][i-1], xy[i][i], xy[i][i+1]}

  const int tid = threadIdx.x;

  // ---- Stage S into padded half-rows; yy[j] ----
  for (int t = tid; t < 500; t += BLOCK) {
    const int r = t / 50, c = t % 50;
    const int src = (r < 5) ? (100 * r + c) : (100 * (r - 5) + 50 + c);
    sS[r * SROW + c] = S[src];
  }
  if (tid < 5) {
    float a = 0.f;
    #pragma unroll 10
    for (int s = 0; s < 100; s += 2) {
      const float2 v = *reinterpret_cast<const float2*>(&S[tid * 100 + s]);
      a = fmaf(v.x, v.x, fmaf(v.y, v.y, a));
    }
    sYY[tid] = a;
  }
  __syncthreads();

  // ---- Per-thread 50-block: direct global x, LDS-broadcast S ----
  const int i0 = (3 * tid) % 5;   // first-half segment role
  const int i1 = (i0 + 2) % 5;    // second-half segment role
  const float* __restrict__ SA0 = &sS[SROW * (i0 > 0 ? i0 - 1 : 0)];
  const float* __restrict__ SA1 = &sS[SROW * i0];
  const float* __restrict__ SA2 = &sS[SROW * (i0 < 4 ? i0 + 1 : 4)];
  const float* __restrict__ SB0 = &sS[SROW * (5 + (i1 > 0 ? i1 - 1 : 0))];
  const float* __restrict__ SB1 = &sS[SROW * (5 + i1)];
  const float* __restrict__ SB2 = &sS[SROW * (5 + (i1 < 4 ? i1 + 1 : 4))];

  const long long bg = 250LL * blockIdx.x + tid;  // global 50-block id
  const long long e0 = 50LL * bg;
  long long A = e0 & ~3LL;          // 16B-aligned load base
  if (A > Q - 60) A = Q - 60;       // clamp: keeps all 14 loads legal; affected
                                    // threads' outputs are guarded out below
  const int sh = (int)(e0 - A);     // 0 or 2 for valid threads

  // Preload 14 aligned float4 (full MLP, one wait)
  float4 v[14];
  #pragma unroll
  for (int k = 0; k < 14; ++k)
    v[k] = *reinterpret_cast<const float4*>(&x[A + 4 * k]);

  float sq = 0.f, A0 = 0.f, A1 = 0.f, A2 = 0.f, B0 = 0.f, B1 = 0.f, B2 = 0.f;
  #pragma unroll
  for (int g = 0; g < 12; ++g) {
    const int t = 4 * g;
    float4 q;  // x[e0+t .. e0+t+3]
    q.x = sh ? v[g].z : v[g].x;
    q.y = sh ? v[g].w : v[g].y;
    q.z = sh ? v[g + 1].x : v[g].z;
    q.w = sh ? v[g + 1].y : v[g].w;

    sq = fmaf(q.x, q.x, fmaf(q.y, q.y, fmaf(q.z, q.z, fmaf(q.w, q.w, sq))));
    float4 y;
    y = *reinterpret_cast<const float4*>(&SA0[t]);
    A0 = fmaf(q.x, y.x, fmaf(q.y, y.y, fmaf(q.z, y.z, fmaf(q.w, y.w, A0))));
    y = *reinterpret_cast<const float4*>(&SA1[t]);
    A1 = fmaf(q.x, y.x, fmaf(q.y, y.y, fmaf(q.z, y.z, fmaf(q.w, y.w, A1))));
    y = *reinterpret_cast<const float4*>(&SA2[t]);
    A2 = fmaf(q.x, y.x, fmaf(q.y, y.y, fmaf(q.z, y.z, fmaf(q.w, y.w, A2))));
    y = *reinterpret_cast<const float4*>(&SB0[t]);
    B0 = fmaf(q.x, y.x, fmaf(q.y, y.y, fmaf(q.z, y.z, fmaf(q.w, y.w, B0))));
    y = *reinterpret_cast<const float4*>(&SB1[t]);
    B1 = fmaf(q.x, y.x, fmaf(q.y, y.y, fmaf(q.z, y.z, fmaf(q.w, y.w, B1))));
    y = *reinterpret_cast<const float4*>(&SB2[t]);
    B2 = fmaf(q.x, y.x, fmaf(q.y, y.y, fmaf(q.z, y.z, fmaf(q.w, y.w, B2))));
  }
  {  // tail t = 48,49 : both shifts read from v[12]
    const float qx = sh ? v[12].z : v[12].x;
    const float qy = sh ? v[12].w : v[12].y;
    sq = fmaf(qx, qx, fmaf(qy, qy, sq));
    float2 y;
    y = *reinterpret_cast<const float2*>(&SA0[48]);
    A0 = fmaf(qx, y.x, fmaf(qy, y.y, A0));
    y = *reinterpret_cast<const float2*>(&SA1[48]);
    A1 = fmaf(qx, y.x, fmaf(qy, y.y, A1));
    y = *reinterpret_cast<const float2*>(&SA2[48]);
    A2 = fmaf(qx, y.x, fmaf(qy, y.y, A2));
    y = *reinterpret_cast<const float2*>(&SB0[48]);
    B0 = fmaf(qx, y.x, fmaf(qy, y.y, B0));
    y = *reinterpret_cast<const float2*>(&SB1[48]);
    B1 = fmaf(qx, y.x, fmaf(qy, y.y, B1));
    y = *reinterpret_cast<const float2*>(&SB2[48]);
    B2 = fmaf(qx, y.x, fmaf(qy, y.y, B2));
  }

  // ---- Neighbor combine via LDS ----
  float4 ex;
  ex.x = sq; ex.y = B0; ex.z = B1; ex.w = B2;
  exch[tid] = ex;
  __syncthreads();
  const int w0 = (tid - 2 * i0) / 5;  // exact division by construction
  if (w0 >= 0 && w0 < NWIN) {         // max needed tid = 253 -> tid+1 safe
    const float4 nx = exch[tid + 1];
    float4 c;
    c.x = sq + nx.x;
    c.y = A0 + nx.y;
    c.z = A1 + nx.z;
    c.w = A2 + nx.w;
    cw[w0 * 5 + i0] = c;
  }
  __syncthreads();

  // ---- DTW + exp (threads 0..49, all wave 0) ----
  float xi = 0.f;
  if (tid < NWIN) {
    const long long w = (long long)blockIdx.x * NWIN + tid;
    if (w < W) {
      const float yy0 = sYY[0], yy1 = sYY[1], yy2 = sYY[2], yy3 = sYY[3],
                  yy4 = sYY[4];
      const float4 c0 = cw[tid * 5 + 0];
      const float4 c1 = cw[tid * 5 + 1];
      const float4 c2 = cw[tid * 5 + 2];
      const float4 c3 = cw[tid * 5 + 3];
      const float4 c4 = cw[tid * 5 + 4];

      const float C00 = c0.x + yy0 - 2.f * c0.z;
      const float C01 = c0.x + yy1 - 2.f * c0.w;
      const float C10 = c1.x + yy0 - 2.f * c1.y;
      const float C11 = c1.x + yy1 - 2.f * c1.z;
      const float C12 = c1.x + yy2 - 2.f * c1.w;
      const float C21 = c2.x + yy1 - 2.f * c2.y;
      const float C22 = c2.x + yy2 - 2.f * c2.z;
      const float C23 = c2.x + yy3 - 2.f * c2.w;
      const float C32 = c3.x + yy2 - 2.f * c3.y;
      const float C33 = c3.x + yy3 - 2.f * c3.z;
      const float C34 = c3.x + yy4 - 2.f * c3.w;
      const float C43 = c4.x + yy3 - 2.f * c4.y;
      const float C44 = c4.x + yy4 - 2.f * c4.z;

      const float c11v = C00;
      const float c12v = C01 + c11v;
      const float c21v = C10 + c11v;
      const float c22v = C11 + fminf(fminf(c12v, c21v), c11v);
      const float c23v = C12 + fminf(c22v, c12v);
      const float c32v = C21 + fminf(c22v, c21v);
      const float c33v = C22 + fminf(fminf(c23v, c32v), c22v);
      const float c34v = C23 + fminf(c33v, c23v);
      const float c43v = C32 + fminf(c33v, c32v);
      const float c44v = C33 + fminf(fminf(c34v, c43v), c33v);
      const float c45v = C34 + fminf(c44v, c34v);
      const float c54v = C43 + fminf(c44v, c43v);
      const float c55v = C44 + fminf(fminf(c45v, c54v), c44v);

      xi = expf(ALPHA_C * sqrtf(fmaxf(c55v, 0.f)));
    }
  }

  if (tid < 64) {
    #pragma unroll
    for (int off = 32; off > 0; off >>= 1) xi += __shfl_down(xi, off);
    if (tid == 0) atomicAdd(out, xi * inv_W);
  }
}

extern "C" void kernel_launch(void* const* d_in, const int* in_sizes, int n_in,
                              void* d_out, int out_size, void* d_ws, size_t ws_size,
                              hipStream_t stream) {
  const float* x = (const float*)d_in[0];
  const float* S = (const float*)d_in[1];
  float* out = (float*)d_out;

  const long long Q = in_sizes[0];
  const int L = in_sizes[1];   // 500
  const int step = L / 2;      // 250
  const long long n = Q - L;
  const int W = (int)((n + step - 1) / step);  // 79998

  hipMemsetAsync(out, 0, sizeof(float), stream);

  const int blocks = (W + NWIN - 1) / NWIN;  // 1600
  softmin_dtw_kernel<<<blocks, BLOCK, 0, stream>>>(x, S, out, Q, W,
                                                   1.0f / (float)W);
}

// Round 6
// 133.114 us; speedup vs baseline: 1.0764x; 1.0054x over previous
//
#include <hip/hip_runtime.h>
#include <math.h>

#define ALPHA_C (-0.01f)
#define BLOCKT 320     // 5 waves; wave v has wave-uniform segment role
#define NWIN 63        // windows resolved per workgroup
#define SROW 52        // padded S half-row stride (208 B, 16B-aligned rows)

__global__ __launch_bounds__(BLOCKT)
void softmin_dtw_kernel(const float* __restrict__ x, const float* __restrict__ S,
                        float* __restrict__ out, long long Q, int W,
                        float inv_W) {
  __shared__ __align__(16) float sS[10 * SROW];  // rows 0-4: S[j][0:50], 5-9: S[j][50:100]
  __shared__ float sYY[5];
  __shared__ __align__(16) float4 exch[320];     // {sq, B0, B1, B2} per 50-block
  __shared__ __align__(16) float4 cw[NWIN * 5];  // {xx, xy[i][i-1], xy[i][i], xy[i][i+1]}

  const int tid = threadIdx.x;

  // ---- Stage S into duplicated, padded half-rows (16B-aligned rows) ----
  for (int t = tid; t < 10 * SROW; t += BLOCKT) {
    const int r = t / SROW, c = t % SROW;
    float vv = 0.f;
    if (c < 50) vv = (r < 5) ? S[100 * r + c] : S[100 * (r - 5) + 50 + c];
    sS[t] = vv;
  }
  if (tid < 5) {
    float a = 0.f;
    #pragma unroll 10
    for (int s = 0; s < 100; s += 2) {
      const float2 vv = *reinterpret_cast<const float2*>(&S[tid * 100 + s]);
      a = fmaf(vv.x, vv.x, fmaf(vv.y, vv.y, a));
    }
    sYY[tid] = a;
  }
  __syncthreads();

  // ---- Role assignment: wave-uniform segment roles ----
  const int v = __builtin_amdgcn_readfirstlane(tid >> 6);  // wave 0..4
  const int l = tid & 63;
  const int b = 5 * l + v;          // this thread's 50-block (bijective over [0,320))
  const int i0 = (3 * v) % 5;       // first-half segment role (wave-uniform)
  const int i1 = (i0 + 2) % 5;      // second-half segment role
  // Wave-uniform LDS row pointers -> pure-broadcast ds_read_b128
  const float* __restrict__ SA0 = &sS[SROW * (i0 > 0 ? i0 - 1 : 0)];
  const float* __restrict__ SA1 = &sS[SROW * i0];
  const float* __restrict__ SA2 = &sS[SROW * (i0 < 4 ? i0 + 1 : 4)];
  const float* __restrict__ SB0 = &sS[SROW * (5 + (i1 > 0 ? i1 - 1 : 0))];
  const float* __restrict__ SB1 = &sS[SROW * (5 + i1)];
  const float* __restrict__ SB2 = &sS[SROW * (5 + (i1 < 4 ? i1 + 1 : 4))];

  // ---- x addressing: 16B-aligned rolling loads, shift-select per parity ----
  const long long base = 15750LL * blockIdx.x;   // NWIN*250
  const long long e0 = base + 50LL * b;
  long long A = e0 & ~3LL;
  if (A > Q - 56) A = (Q - 56) & ~3LL;  // clamp keeps all 14 loads legal; affected
                                        // threads only feed windows >= W (discarded)
  const int sh = (int)(e0 - A);         // 0 or 2 for unclamped threads

  float4 rcur = *reinterpret_cast<const float4*>(&x[A]);
  float4 rnxt = *reinterpret_cast<const float4*>(&x[A + 4]);

  float sq = 0.f, A0 = 0.f, A1 = 0.f, A2 = 0.f, B0 = 0.f, B1 = 0.f, B2 = 0.f;

  #pragma unroll
  for (int k = 0; k < 12; ++k) {
    // depth-2 prefetch: load r_{k+2} now, consumed two iterations later
    const float4 rfut = *reinterpret_cast<const float4*>(&x[A + 4 * k + 8]);

    float4 q;  // x[e0 + 4k .. e0 + 4k + 3]
    q.x = sh ? rcur.z : rcur.x;
    q.y = sh ? rcur.w : rcur.y;
    q.z = sh ? rnxt.x : rcur.z;
    q.w = sh ? rnxt.y : rcur.w;

    const int t4 = 4 * k;
    sq = fmaf(q.x, q.x, fmaf(q.y, q.y, fmaf(q.z, q.z, fmaf(q.w, q.w, sq))));
    float4 y;
    y = *reinterpret_cast<const float4*>(&SA0[t4]);
    A0 = fmaf(q.x, y.x, fmaf(q.y, y.y, fmaf(q.z, y.z, fmaf(q.w, y.w, A0))));
    y = *reinterpret_cast<const float4*>(&SA1[t4]);
    A1 = fmaf(q.x, y.x, fmaf(q.y, y.y, fmaf(q.z, y.z, fmaf(q.w, y.w, A1))));
    y = *reinterpret_cast<const float4*>(&SA2[t4]);
    A2 = fmaf(q.x, y.x, fmaf(q.y, y.y, fmaf(q.z, y.z, fmaf(q.w, y.w, A2))));
    y = *reinterpret_cast<const float4*>(&SB0[t4]);
    B0 = fmaf(q.x, y.x, fmaf(q.y, y.y, fmaf(q.z, y.z, fmaf(q.w, y.w, B0))));
    y = *reinterpret_cast<const float4*>(&SB1[t4]);
    B1 = fmaf(q.x, y.x, fmaf(q.y, y.y, fmaf(q.z, y.z, fmaf(q.w, y.w, B1))));
    y = *reinterpret_cast<const float4*>(&SB2[t4]);
    B2 = fmaf(q.x, y.x, fmaf(q.y, y.y, fmaf(q.z, y.z, fmaf(q.w, y.w, B2))));

    rcur = rnxt;
    rnxt = rfut;
  }
  {  // tail columns 48,49: both parities live in r12 (= rcur after loop)
    const float qx = sh ? rcur.z : rcur.x;
    const float qy = sh ? rcur.w : rcur.y;
    sq = fmaf(qx, qx, fmaf(qy, qy, sq));
    float2 y;
    y = *reinterpret_cast<const float2*>(&SA0[48]);
    A0 = fmaf(qx, y.x, fmaf(qy, y.y, A0));
    y = *reinterpret_cast<const float2*>(&SA1[48]);
    A1 = fmaf(qx, y.x, fmaf(qy, y.y, A1));
    y = *reinterpret_cast<const float2*>(&SA2[48]);
    A2 = fmaf(qx, y.x, fmaf(qy, y.y, A2));
    y = *reinterpret_cast<const float2*>(&SB0[48]);
    B0 = fmaf(qx, y.x, fmaf(qy, y.y, B0));
    y = *reinterpret_cast<const float2*>(&SB1[48]);
    B1 = fmaf(qx, y.x, fmaf(qy, y.y, B1));
    y = *reinterpret_cast<const float2*>(&SB2[48]);
    B2 = fmaf(qx, y.x, fmaf(qy, y.y, B2));
  }

  // ---- Neighbor combine via LDS (validated in R3/R4) ----
  {
    float4 ex;
    ex.x = sq; ex.y = B0; ex.z = B1; ex.w = B2;
    exch[b] = ex;
  }
  __syncthreads();
  const int w0 = (b - 2 * i0) / 5;   // exact division by construction
  if (w0 >= 0 && w0 < NWIN) {        // b=319 -> w0=63 skipped, so exch[b+1] safe
    const float4 nx = exch[b + 1];
    float4 c;
    c.x = sq + nx.x;
    c.y = A0 + nx.y;
    c.z = A1 + nx.z;
    c.w = A2 + nx.w;
    cw[w0 * 5 + i0] = c;
  }
  __syncthreads();

  // ---- DTW + exp per window (wave 0) ----
  float xi = 0.f;
  if (tid < NWIN) {
    const long long w = (long long)blockIdx.x * NWIN + tid;
    if (w < W) {
      const float yy0 = sYY[0], yy1 = sYY[1], yy2 = sYY[2], yy3 = sYY[3],
                  yy4 = sYY[4];
      const float4 c0 = cw[tid * 5 + 0];
      const float4 c1 = cw[tid * 5 + 1];
      const float4 c2 = cw[tid * 5 + 2];
      const float4 c3 = cw[tid * 5 + 3];
      const float4 c4 = cw[tid * 5 + 4];

      const float C00 = c0.x + yy0 - 2.f * c0.z;
      const float C01 = c0.x + yy1 - 2.f * c0.w;
      const float C10 = c1.x + yy0 - 2.f * c1.y;
      const float C11 = c1.x + yy1 - 2.f * c1.z;
      const float C12 = c1.x + yy2 - 2.f * c1.w;
      const float C21 = c2.x + yy1 - 2.f * c2.y;
      const float C22 = c2.x + yy2 - 2.f * c2.z;
      const float C23 = c2.x + yy3 - 2.f * c2.w;
      const float C32 = c3.x + yy2 - 2.f * c3.y;
      const float C33 = c3.x + yy3 - 2.f * c3.z;
      const float C34 = c3.x + yy4 - 2.f * c3.w;
      const float C43 = c4.x + yy3 - 2.f * c4.y;
      const float C44 = c4.x + yy4 - 2.f * c4.z;

      const float c11v = C00;
      const float c12v = C01 + c11v;
      const float c21v = C10 + c11v;
      const float c22v = C11 + fminf(fminf(c12v, c21v), c11v);
      const float c23v = C12 + fminf(c22v, c12v);
      const float c32v = C21 + fminf(c22v, c21v);
      const float c33v = C22 + fminf(fminf(c23v, c32v), c22v);
      const float c34v = C23 + fminf(c33v, c23v);
      const float c43v = C32 + fminf(c33v, c32v);
      const float c44v = C33 + fminf(fminf(c34v, c43v), c33v);
      const float c45v = C34 + fminf(c44v, c34v);
      const float c54v = C43 + fminf(c44v, c43v);
      const float c55v = C44 + fminf(fminf(c45v, c54v), c44v);

      xi = expf(ALPHA_C * sqrtf(fmaxf(c55v, 0.f)));
    }
  }

  if (tid < 64) {
    #pragma unroll
    for (int off = 32; off > 0; off >>= 1) xi += __shfl_down(xi, off);
    if (tid == 0) atomicAdd(out, xi * inv_W);
  }
}

extern "C" void kernel_launch(void* const* d_in, const int* in_sizes, int n_in,
                              void* d_out, int out_size, void* d_ws, size_t ws_size,
                              hipStream_t stream) {
  const float* x = (const float*)d_in[0];
  const float* S = (const float*)d_in[1];
  float* out = (float*)d_out;

  const long long Q = in_sizes[0];
  const int L = in_sizes[1];   // 500
  const int step = L / 2;      // 250
  const long long n = Q - L;
  const int W = (int)((n + step - 1) / step);  // 79998

  hipMemsetAsync(out, 0, sizeof(float), stream);

  const int blocks = (W + NWIN - 1) / NWIN;  // 1270
  softmin_dtw_kernel<<<blocks, BLOCKT, 0, stream>>>(x, S, out, Q, W,
                                                    1.0f / (float)W);
}